// Round 7
// baseline (3500.607 us; speedup 1.0000x reference)
//
#include <hip/hip_runtime.h>

typedef unsigned int u32;

// ---------------------------------------------------------------- zero out
__global__ void zero_k(float* p, int n) {
    int i = blockIdx.x * blockDim.x + threadIdx.x;
    int st = gridDim.x * blockDim.x;
    for (; i < n; i += st) p[i] = 0.0f;
}

// ---------------------------------------------------------------- edge kernel
// one wave per edge (grid-strided); fp32 atomicAdd directly into d_out.
__global__ __launch_bounds__(512, 1) void edge_k(
    const int* __restrict__ src, const int* __restrict__ dst,
    const float* __restrict__ r_ij, const float* __restrict__ z0g,
    const float* __restrict__ z1g, const float* __restrict__ emb,
    const float* __restrict__ Wenc, const float* __restrict__ benc,
    const float* __restrict__ Wsrc, const float* __restrict__ bsrc,
    const float* __restrict__ Wdst, const float* __restrict__ bdst,
    const float* __restrict__ Wgate, const float* __restrict__ bgate,
    const float* __restrict__ Ws, const float* __restrict__ Wv,
    float* __restrict__ out, int N, int E)
{
    __shared__ float sWsrc[4096];   // 16 KB
    __shared__ float sWdst[4096];   // 16 KB
    __shared__ float sWg[16384];    // 64 KB  [k][j*64+c]
    __shared__ float sWs[4096];     // 16 KB
    __shared__ float sWv[4096];     // 16 KB
    __shared__ float sWe[512];      //  2 KB
    __shared__ float sB[64];        // benc+bsrc+bdst
    __shared__ float sBg[256];
    __shared__ int sFl[2];

    if (threadIdx.x == 0) {
        // int64 detection: odd u32 words all zero over first 64 entries
        const u32* ps = (const u32*)src;
        const u32* pd = (const u32*)dst;
        int s64 = 1, d64 = 1;
        for (int i = 1; i < 128; i += 2) {
            if (ps[i] != 0u) s64 = 0;
            if (pd[i] != 0u) d64 = 0;
        }
        sFl[0] = s64;
        sFl[1] = d64;
    }
    for (int i = threadIdx.x; i < 4096; i += 512) {
        sWsrc[i] = Wsrc[i];
        sWdst[i] = Wdst[i];
        sWs[i] = Ws[i];
        sWv[i] = Wv[i];
    }
    for (int i = threadIdx.x; i < 16384; i += 512) sWg[i] = Wgate[i];
    for (int i = threadIdx.x; i < 512; i += 512) sWe[i] = Wenc[i];
    if (threadIdx.x < 64)
        sB[threadIdx.x] = benc[threadIdx.x] + bsrc[threadIdx.x] + bdst[threadIdx.x];
    if (threadIdx.x < 256) sBg[threadIdx.x] = bgate[threadIdx.x];
    __syncthreads();

    const int wid = threadIdx.x >> 6, lane = threadIdx.x & 63;
    const int i64s = sFl[0], i64d = sFl[1];

    for (int e = blockIdx.x * 8 + wid; e < E; e += gridDim.x * 8) {
        const int s = i64s ? src[2 * e] : src[e];
        const int t = i64d ? dst[2 * e] : dst[e];
        if (s < 0 || s >= N || t < 0 || t >= N) continue;   // safety guard

        // dist_emb = emb[s]@Wsrc + emb[t]@Wdst + radial(d)@Wenc + (b_enc+b_src+b_dst)
        const float es = emb[s * 64 + lane];
        const float et = emb[t * 64 + lane];
        float de = sB[lane];
        #pragma unroll 8
        for (int k = 0; k < 64; ++k) {
            de += __shfl(es, k, 64) * sWsrc[(k << 6) + lane];
            de += __shfl(et, k, 64) * sWdst[(k << 6) + lane];
        }
        const float r0 = r_ij[e * 3 + 0];
        const float r1 = r_ij[e * 3 + 1];
        const float r2 = r_ij[e * 3 + 2];
        const float d = sqrtf(r0 * r0 + r1 * r1 + r2 * r2);
        #pragma unroll
        for (int m = 0; m < 8; ++m) {
            const float mu = (2.0f / 7.0f) * (float)m;   // linspace(0, 2, 8)
            const float tt = (d - mu) * 4.0f;            // / sigma, sigma = 0.25
            de += __expf(-tt * tt) * sWe[m * 64 + lane];
        }

        // r_hat = v/sqrt(1+|v|^2), v = r_ij * (7/R0) = r_ij*3.5
        const float v0 = r0 * 3.5f, v1 = r1 * 3.5f, v2 = r2 * 3.5f;
        const float inv = rsqrtf(1.0f + v0 * v0 + v1 * v1 + v2 * v2);
        const float h0 = v0 * inv, h1 = v1 * inv, h2 = v2 * inv;

        // gather dst features
        const float z0v = z0g[t * 64 + lane];
        const float za = z1g[t * 192 + lane];
        const float zb = z1g[t * 192 + 64 + lane];
        const float zc = z1g[t * 192 + 128 + lane];
        const float uu = h0 * za + h1 * zb + h2 * zc;    // r_hat · z1_j

        // gate = dist_emb @ W_gate + b_gate  (4 columns per lane)
        float g0 = sBg[lane], g1 = sBg[64 + lane], g2 = sBg[128 + lane], g3 = sBg[192 + lane];
        #pragma unroll 8
        for (int k = 0; k < 64; ++k) {
            const float dk = __shfl(de, k, 64);
            const float* w = &sWg[(k << 8) + lane];
            g0 += dk * w[0];
            g1 += dk * w[64];
            g2 += dk * w[128];
            g3 += dk * w[192];
        }

        const float smsg = g0 * z0v + g1 * uu;
        const float vm0 = g2 * za + g3 * h0 * z0v;
        const float vm1 = g2 * zb + g3 * h1 * z0v;
        const float vm2 = g2 * zc + g3 * h2 * z0v;

        // psi0 = smsg @ W_s ; psi1_i = vm_i @ W_v
        float p0 = 0.f, q0 = 0.f, q1 = 0.f, q2 = 0.f;
        #pragma unroll 8
        for (int k = 0; k < 64; ++k) {
            const float sk = __shfl(smsg, k, 64);
            const float a = __shfl(vm0, k, 64);
            const float b = __shfl(vm1, k, 64);
            const float c = __shfl(vm2, k, 64);
            p0 += sk * sWs[(k << 6) + lane];
            const float wv = sWv[(k << 6) + lane];
            q0 += a * wv;
            q1 += b * wv;
            q2 += c * wv;
        }

        // scatter-add to source node, fp32 directly into d_out
        atomicAdd(&out[s * 64 + lane], p0);
        const int b1 = N * 64 + s * 192 + lane;
        atomicAdd(&out[b1], q0);
        atomicAdd(&out[b1 + 64], q1);
        atomicAdd(&out[b1 + 128], q2);
    }
}

extern "C" void kernel_launch(void* const* d_in, const int* in_sizes, int n_in,
                              void* d_out, int out_size, void* d_ws, size_t ws_size,
                              hipStream_t stream) {
    const int* src = (const int*)d_in[0];
    const int* dst = (const int*)d_in[1];
    const float* r_ij = (const float*)d_in[2];
    const float* z0g  = (const float*)d_in[3];
    const float* z1g  = (const float*)d_in[4];
    const float* emb  = (const float*)d_in[5];
    const float* Wenc = (const float*)d_in[6];
    const float* benc = (const float*)d_in[7];
    const float* Wsrc = (const float*)d_in[8];
    const float* bsrc = (const float*)d_in[9];
    const float* Wdst = (const float*)d_in[10];
    const float* bdst = (const float*)d_in[11];
    const float* Wgate = (const float*)d_in[12];
    const float* bgate = (const float*)d_in[13];
    const float* Ws = (const float*)d_in[14];
    const float* Wv = (const float*)d_in[15];

    const int N = out_size / 256;                    // out0 N*64 + out1 N*192
    int E = in_sizes[0];
    if (in_sizes[2] / 3 < E) E = in_sizes[2] / 3;    // robustness

    zero_k<<<2048, 256, 0, stream>>>((float*)d_out, out_size);
    edge_k<<<2048, 512, 0, stream>>>(src, dst, r_ij, z0g, z1g, emb, Wenc, benc,
                                     Wsrc, bsrc, Wdst, bdst, Wgate, bgate, Ws, Wv,
                                     (float*)d_out, N, E);
}